// Round 8
// baseline (184.105 us; speedup 1.0000x reference)
//
#include <hip/hip_runtime.h>

#define NN   50000
#define NE   200000
#define NE2  100000   // NE/2
#define INC  16
#define HIDC 32
#define EDGED 8
#define OUTC 32
#define MLPH 128
#define NACT 32

#define NPART 196   // ceil(NN / 256)
#define NODE_T 64

// ---- prep: transpose We [8][512] -> We_t [512][8] ----
__global__ __launch_bounds__(256) void transpose_we(const float* __restrict__ We,
                                                    float* __restrict__ We_t) {
    int idx = blockIdx.x * blockDim.x + threadIdx.x;
    if (idx < EDGED * INC * HIDC) {
        int d = idx / (INC * HIDC), ih = idx % (INC * HIDC);
        We_t[ih * EDGED + d] = We[idx];
    }
}

// ---- degree histogram ----
__global__ __launch_bounds__(256) void hist_kernel(const int* __restrict__ edst,
                                                   int* __restrict__ deg) {
    int e = blockIdx.x * blockDim.x + threadIdx.x;
    if (e < NE) atomicAdd(&deg[edst[e]], 1);
}

// ---- scan pass 1: per-block sums ----
__global__ __launch_bounds__(256) void partial_kernel(const int* __restrict__ deg,
                                                      int* __restrict__ partials) {
    __shared__ int sm[256];
    int t = threadIdx.x, i = blockIdx.x * 256 + t;
    sm[t] = (i < NN) ? deg[i] : 0;
    __syncthreads();
    #pragma unroll
    for (int off = 128; off > 0; off >>= 1) {
        if (t < off) sm[t] += sm[t + off];
        __syncthreads();
    }
    if (t == 0) partials[blockIdx.x] = sm[0];
}

// ---- scan pass 2: exclusive scan of 196 partials ----
__global__ __launch_bounds__(256) void scan_partials_kernel(const int* __restrict__ partials,
                                                            int* __restrict__ poff) {
    __shared__ int sm[256];
    int t = threadIdx.x;
    sm[t] = (t < NPART) ? partials[t] : 0;
    __syncthreads();
    for (int off = 1; off < 256; off <<= 1) {
        int v = (t >= off) ? sm[t - off] : 0;
        __syncthreads();
        sm[t] += v;
        __syncthreads();
    }
    poff[t] = (t == 0) ? 0 : sm[t - 1];
}

// ---- scan pass 3: block-local scan + base -> row_off ----
__global__ __launch_bounds__(256) void rowoff_kernel(const int* __restrict__ deg,
                                                     const int* __restrict__ poff,
                                                     int* __restrict__ row_off) {
    __shared__ int sm[256];
    int t = threadIdx.x, i = blockIdx.x * 256 + t;
    int d = (i < NN) ? deg[i] : 0;
    sm[t] = d;
    __syncthreads();
    for (int off = 1; off < 256; off <<= 1) {
        int v = (t >= off) ? sm[t - off] : 0;
        __syncthreads();
        sm[t] += v;
        __syncthreads();
    }
    int excl = sm[t] - d + poff[blockIdx.x];
    if (i < NN) {
        row_off[i] = excl;
        if (i == NN - 1) row_off[NN] = excl + d;   // == NE
    }
}

// ---- build permutation: eperm[pos] = e (4-B scattered writes, cheap) ----
__global__ __launch_bounds__(256) void build_perm_kernel(const int* __restrict__ edst,
                                                         const int* __restrict__ row_off,
                                                         int* __restrict__ cursor,
                                                         int* __restrict__ eperm) {
    int e = blockIdx.x * blockDim.x + threadIdx.x;
    if (e < NE) {
        int dst = edst[e];
        int pos = row_off[dst] + atomicAdd(&cursor[dst], 1);
        eperm[pos] = e;
    }
}

// ---- edge kernel: 2 edges per thread (share every weight ds_read);
//      writes msg_buf in EDGE ORDER -> fully coalesced, zero atomics. ----
__global__ __launch_bounds__(256, 3) void edge_kernel(
    const float* __restrict__ x,
    const int*   __restrict__ esrc,
    const float* __restrict__ ea,
    const float* __restrict__ We_t,   // [512][8]
    const float* __restrict__ be,
    float*       __restrict__ msg_buf) // [NE][32], edge order
{
    __shared__ float sWe[EDGED * INC * HIDC];   // 16 KB, [ih][d]
    __shared__ float sbe[INC * HIDC];           //  2 KB

    {
        float4* d4 = reinterpret_cast<float4*>(sWe);
        const float4* s4 = reinterpret_cast<const float4*>(We_t);
        for (int i = threadIdx.x; i < (EDGED * INC * HIDC) / 4; i += 256) d4[i] = s4[i];
        float4* b4 = reinterpret_cast<float4*>(sbe);
        const float4* t4 = reinterpret_cast<const float4*>(be);
        for (int i = threadIdx.x; i < (INC * HIDC) / 4; i += 256) b4[i] = t4[i];
    }
    __syncthreads();

    int t = blockIdx.x * blockDim.x + threadIdx.x;
    if (t >= NE2) return;
    int e0 = t, e1 = t + NE2;

    int src0 = esrc[e0], src1 = esrc[e1];

    const float4* ea40 = reinterpret_cast<const float4*>(ea) + (size_t)e0 * 2;
    const float4* ea41 = reinterpret_cast<const float4*>(ea) + (size_t)e1 * 2;
    float4 a0 = ea40[0], a1 = ea40[1], b0 = ea41[0], b1 = ea41[1];
    float ev0[8] = {a0.x,a0.y,a0.z,a0.w,a1.x,a1.y,a1.z,a1.w};
    float ev1[8] = {b0.x,b0.y,b0.z,b0.w,b1.x,b1.y,b1.z,b1.w};

    float msg0[HIDC], msg1[HIDC];
    #pragma unroll
    for (int h = 0; h < HIDC; ++h) { msg0[h] = 0.f; msg1[h] = 0.f; }

    const float4* x40 = reinterpret_cast<const float4*>(x) + (size_t)src0 * 4;
    const float4* x41 = reinterpret_cast<const float4*>(x) + (size_t)src1 * 4;

    for (int i4 = 0; i4 < 4; ++i4) {
        float4 xv0 = x40[i4], xv1 = x41[i4];
        float xs0[4] = {xv0.x, xv0.y, xv0.z, xv0.w};
        float xs1[4] = {xv1.x, xv1.y, xv1.z, xv1.w};
        #pragma unroll
        for (int ii = 0; ii < 4; ++ii) {
            int i = i4 * 4 + ii;
            const float* wbase = sWe + i * (HIDC * EDGED);
            const float* becol = sbe + i * HIDC;
            float xi0 = xs0[ii], xi1 = xs1[ii];
            #pragma unroll
            for (int h = 0; h < HIDC; ++h) {
                const float* wr = wbase + h * EDGED;   // shared by both edges
                float bv = becol[h];
                float w0 = bv, w1 = bv;
                #pragma unroll
                for (int d = 0; d < EDGED; ++d) {
                    float wd = wr[d];
                    w0 = fmaf(ev0[d], wd, w0);
                    w1 = fmaf(ev1[d], wd, w1);
                }
                w0 = fmaxf(w0, 0.f);
                w1 = fmaxf(w1, 0.f);
                msg0[h] = fmaf(xi0, w0, msg0[h]);
                msg1[h] = fmaf(xi1, w1, msg1[h]);
            }
        }
    }

    float4* m0 = reinterpret_cast<float4*>(msg_buf) + (size_t)e0 * 8;
    float4* m1 = reinterpret_cast<float4*>(msg_buf) + (size_t)e1 * 8;
    #pragma unroll
    for (int h4 = 0; h4 < 8; ++h4) {
        m0[h4] = make_float4(msg0[h4*4+0], msg0[h4*4+1], msg0[h4*4+2], msg0[h4*4+3]);
        m1[h4] = make_float4(msg1[h4*4+0], msg1[h4*4+1], msg1[h4*4+2], msg1[h4*4+3]);
    }
}

// ---- fused node kernel: 1 thread/node; weights in LDS; gathers messages
//      via eperm (scattered FULL-LINE 128B reads -> no amplification). ----
#define S_WROOT 0        // 512
#define S_WLIN  512      // 1024
#define S_WQ1   1536     // 4096  [32][128]
#define S_WQ2   5632     // 4096  [128][32]
#define S_BCONV 9728     // 32
#define S_GAMMA 9760     // 32
#define S_BETA  9792     // 32
#define S_BLIN  9824     // 32
#define S_BQ1   9856     // 128
#define S_BQ2   9984     // 32
#define S_TOT   10016    // floats = 40064 B

__global__ __launch_bounds__(NODE_T, 1) void node_fused_kernel(
    const float* __restrict__ x,
    const float* __restrict__ msg_buf,   // [NE][32], edge order
    const int*   __restrict__ eperm,     // [NE], sorted->edge
    const int*   __restrict__ row_off,
    const float* __restrict__ Wroot,
    const float* __restrict__ bconv,
    const float* __restrict__ gamma,
    const float* __restrict__ beta,
    const float* __restrict__ Wlin,
    const float* __restrict__ blin,
    const float* __restrict__ Wq1,       // [32][128]
    const float* __restrict__ bq1,
    const float* __restrict__ Wq2,       // [128][32]
    const float* __restrict__ bq2,
    float* __restrict__ out)
{
    __shared__ float sm[S_TOT];
    {
        float4* d4 = reinterpret_cast<float4*>(sm);
        const float4* s;
        int t = threadIdx.x;
        s = reinterpret_cast<const float4*>(Wroot);
        for (int i = t; i < 512/4; i += NODE_T) d4[S_WROOT/4 + i] = s[i];
        s = reinterpret_cast<const float4*>(Wlin);
        for (int i = t; i < 1024/4; i += NODE_T) d4[S_WLIN/4 + i] = s[i];
        s = reinterpret_cast<const float4*>(Wq1);
        for (int i = t; i < 4096/4; i += NODE_T) d4[S_WQ1/4 + i] = s[i];
        s = reinterpret_cast<const float4*>(Wq2);
        for (int i = t; i < 4096/4; i += NODE_T) d4[S_WQ2/4 + i] = s[i];
        s = reinterpret_cast<const float4*>(bconv);
        if (t < 8)  d4[S_BCONV/4 + t] = s[t];
        s = reinterpret_cast<const float4*>(gamma);
        if (t < 8)  d4[S_GAMMA/4 + t] = s[t];
        s = reinterpret_cast<const float4*>(beta);
        if (t < 8)  d4[S_BETA/4 + t] = s[t];
        s = reinterpret_cast<const float4*>(blin);
        if (t < 8)  d4[S_BLIN/4 + t] = s[t];
        s = reinterpret_cast<const float4*>(bq1);
        if (t < 32) d4[S_BQ1/4 + t] = s[t];
        s = reinterpret_cast<const float4*>(bq2);
        if (t < 8)  d4[S_BQ2/4 + t] = s[t];
    }
    __syncthreads();

    int n = blockIdx.x * NODE_T + threadIdx.x;
    if (n >= NN) return;

    // ---- h = bconv + sum(gathered msg rows) + x @ Wroot ----
    float h[HIDC];
    #pragma unroll
    for (int c = 0; c < HIDC; ++c) h[c] = sm[S_BCONV + c];

    int start = row_off[n], end = row_off[n + 1];
    for (int k = start; k < end; ++k) {
        int e = eperm[k];
        const float4* m4 = reinterpret_cast<const float4*>(msg_buf) + (size_t)e * 8;
        #pragma unroll
        for (int c4 = 0; c4 < 8; ++c4) {
            float4 m = m4[c4];
            h[c4 * 4 + 0] += m.x;
            h[c4 * 4 + 1] += m.y;
            h[c4 * 4 + 2] += m.z;
            h[c4 * 4 + 3] += m.w;
        }
    }

    const float4* x4 = reinterpret_cast<const float4*>(x) + (size_t)n * 4;
    #pragma unroll
    for (int i4 = 0; i4 < 4; ++i4) {
        float4 xv = x4[i4];
        float xs[4] = {xv.x, xv.y, xv.z, xv.w};
        #pragma unroll
        for (int ii = 0; ii < 4; ++ii) {
            const float* wr = sm + S_WROOT + (i4 * 4 + ii) * HIDC;
            float xi = xs[ii];
            #pragma unroll
            for (int c = 0; c < HIDC; ++c)
                h[c] = fmaf(xi, wr[c], h[c]);
        }
    }

    // ---- LayerNorm + ReLU ----
    float mu = 0.f;
    #pragma unroll
    for (int c = 0; c < HIDC; ++c) mu += h[c];
    mu *= (1.f / HIDC);
    float var = 0.f;
    #pragma unroll
    for (int c = 0; c < HIDC; ++c) { float t = h[c] - mu; var = fmaf(t, t, var); }
    var *= (1.f / HIDC);
    float rstd = rsqrtf(var + 1e-5f);
    #pragma unroll
    for (int c = 0; c < HIDC; ++c)
        h[c] = fmaxf(fmaf((h[c] - mu) * rstd, sm[S_GAMMA + c], sm[S_BETA + c]), 0.f);

    // ---- feat = h @ Wlin + blin ----
    float f[OUTC];
    #pragma unroll
    for (int a = 0; a < OUTC; ++a) f[a] = sm[S_BLIN + a];
    #pragma unroll
    for (int k = 0; k < HIDC; ++k) {
        float hk = h[k];
        const float* wr = sm + S_WLIN + k * OUTC;
        #pragma unroll
        for (int a = 0; a < OUTC; ++a)
            f[a] = fmaf(hk, wr[a], f[a]);
    }

    // ---- q_head in 4 m-chunks of 32 ----
    float q[NACT];
    #pragma unroll
    for (int a = 0; a < NACT; ++a) q[a] = sm[S_BQ2 + a];

    for (int c = 0; c < 4; ++c) {
        const float* w1c = sm + S_WQ1 + c * 32;
        const float* b1c = sm + S_BQ1 + c * 32;
        const float* w2c = sm + S_WQ2 + c * 32 * NACT;

        float acc[32];
        #pragma unroll
        for (int j = 0; j < 32; ++j) acc[j] = b1c[j];

        #pragma unroll
        for (int k = 0; k < 32; ++k) {
            float fk = f[k];
            const float* wr = w1c + k * MLPH;
            #pragma unroll
            for (int j = 0; j < 32; ++j)
                acc[j] = fmaf(fk, wr[j], acc[j]);
        }

        #pragma unroll
        for (int j = 0; j < 32; ++j) {
            float t = fmaxf(acc[j], 0.f);
            const float* wr = w2c + j * NACT;
            #pragma unroll
            for (int a = 0; a < NACT; ++a)
                q[a] = fmaf(t, wr[a], q[a]);
        }
    }

    float4* o4 = reinterpret_cast<float4*>(out) + (size_t)n * 8;
    #pragma unroll
    for (int a4 = 0; a4 < 8; ++a4)
        o4[a4] = make_float4(q[a4 * 4 + 0], q[a4 * 4 + 1], q[a4 * 4 + 2], q[a4 * 4 + 3]);
}

extern "C" void kernel_launch(void* const* d_in, const int* in_sizes, int n_in,
                              void* d_out, int out_size, void* d_ws, size_t ws_size,
                              hipStream_t stream) {
    const float* x     = (const float*)d_in[0];
    const int*   esrc  = (const int*)d_in[1];
    const int*   edst  = (const int*)d_in[2];
    const float* ea    = (const float*)d_in[3];
    const float* We    = (const float*)d_in[4];
    const float* be    = (const float*)d_in[5];
    const float* Wroot = (const float*)d_in[6];
    const float* bconv = (const float*)d_in[7];
    const float* gamma = (const float*)d_in[8];
    const float* beta  = (const float*)d_in[9];
    const float* Wlin  = (const float*)d_in[10];
    const float* blin  = (const float*)d_in[11];
    const float* Wq1   = (const float*)d_in[12];
    const float* bq1   = (const float*)d_in[13];
    const float* Wq2   = (const float*)d_in[14];
    const float* bq2   = (const float*)d_in[15];
    float* out = (float*)d_out;

    // workspace layout
    char* ws = (char*)d_ws;
    float* We_t    = (float*)(ws + 0);         //  16 KB
    int*   deg     = (int*)(ws + 16384);       // 200704 B
    int*   cursor  = (int*)(ws + 217088);      // 200704 B
    int*   row_off = (int*)(ws + 417792);      // 201728 B
    int*   partials= (int*)(ws + 619520);      // 1 KB
    int*   poff    = (int*)(ws + 620544);      // 1 KB
    int*   eperm   = (int*)(ws + 621568);      // 800 KB (pad to 802816)
    float* msg_buf = (float*)(ws + 621568 + 802816);  // 25.6 MB

    hipMemsetAsync(deg, 0, 2 * 200704, stream);   // deg + cursor (adjacent)

    transpose_we<<<16, 256, 0, stream>>>(We, We_t);
    hist_kernel<<<(NE + 255) / 256, 256, 0, stream>>>(edst, deg);
    partial_kernel<<<NPART, 256, 0, stream>>>(deg, partials);
    scan_partials_kernel<<<1, 256, 0, stream>>>(partials, poff);
    rowoff_kernel<<<NPART, 256, 0, stream>>>(deg, poff, row_off);
    build_perm_kernel<<<(NE + 255) / 256, 256, 0, stream>>>(edst, row_off, cursor, eperm);
    edge_kernel<<<(NE2 + 255) / 256, 256, 0, stream>>>(x, esrc, ea, We_t, be, msg_buf);
    node_fused_kernel<<<(NN + NODE_T - 1) / NODE_T, NODE_T, 0, stream>>>(
        x, msg_buf, eperm, row_off, Wroot, bconv, gamma, beta,
        Wlin, blin, Wq1, bq1, Wq2, bq2, out);
}

// Round 9
// 178.103 us; speedup vs baseline: 1.0337x; 1.0337x over previous
//
#include <hip/hip_runtime.h>

#define NN   50000
#define NE   200000
#define INC  16
#define HIDC 32
#define EDGED 8
#define OUTC 32
#define MLPH 128
#define NACT 32

#define NPART 196   // ceil(NN / 256)

// ---- degree histogram ----
__global__ __launch_bounds__(256) void hist_kernel(const int* __restrict__ edst,
                                                   int* __restrict__ deg) {
    int e = blockIdx.x * blockDim.x + threadIdx.x;
    if (e < NE) atomicAdd(&deg[edst[e]], 1);
}

// ---- scan pass 1: per-block sums ----
__global__ __launch_bounds__(256) void partial_kernel(const int* __restrict__ deg,
                                                      int* __restrict__ partials) {
    __shared__ int sm[256];
    int t = threadIdx.x, i = blockIdx.x * 256 + t;
    sm[t] = (i < NN) ? deg[i] : 0;
    __syncthreads();
    #pragma unroll
    for (int off = 128; off > 0; off >>= 1) {
        if (t < off) sm[t] += sm[t + off];
        __syncthreads();
    }
    if (t == 0) partials[blockIdx.x] = sm[0];
}

// ---- scan pass 2: exclusive scan of 196 partials ----
__global__ __launch_bounds__(256) void scan_partials_kernel(const int* __restrict__ partials,
                                                            int* __restrict__ poff) {
    __shared__ int sm[256];
    int t = threadIdx.x;
    sm[t] = (t < NPART) ? partials[t] : 0;
    __syncthreads();
    for (int off = 1; off < 256; off <<= 1) {
        int v = (t >= off) ? sm[t - off] : 0;
        __syncthreads();
        sm[t] += v;
        __syncthreads();
    }
    poff[t] = (t == 0) ? 0 : sm[t - 1];
}

// ---- scan pass 3: block-local scan + base -> row_off ----
__global__ __launch_bounds__(256) void rowoff_kernel(const int* __restrict__ deg,
                                                     const int* __restrict__ poff,
                                                     int* __restrict__ row_off) {
    __shared__ int sm[256];
    int t = threadIdx.x, i = blockIdx.x * 256 + t;
    int d = (i < NN) ? deg[i] : 0;
    sm[t] = d;
    __syncthreads();
    for (int off = 1; off < 256; off <<= 1) {
        int v = (t >= off) ? sm[t - off] : 0;
        __syncthreads();
        sm[t] += v;
        __syncthreads();
    }
    int excl = sm[t] - d + poff[blockIdx.x];
    if (i < NN) {
        row_off[i] = excl;
        if (i == NN - 1) row_off[NN] = excl + d;   // == NE
    }
}

// ---- build permutation: eperm[pos] = e ----
__global__ __launch_bounds__(256) void build_perm_kernel(const int* __restrict__ edst,
                                                         const int* __restrict__ row_off,
                                                         int* __restrict__ cursor,
                                                         int* __restrict__ eperm) {
    int e = blockIdx.x * blockDim.x + threadIdx.x;
    if (e < NE) {
        int dst = edst[e];
        int pos = row_off[dst] + atomicAdd(&cursor[dst], 1);
        eperm[pos] = e;
    }
}

// ---- edge kernel: 4 lanes per edge, lane owns 8 channels.
//      LDS weights in l-staggered blocks (stride 1032 words -> bank-quads
//      {0,8,16,24}, conflict-free 16-way broadcast). 800K threads. ----
__global__ __launch_bounds__(256, 4) void edge_q_kernel(
    const float* __restrict__ x,
    const int*   __restrict__ esrc,
    const float* __restrict__ ea,
    const float* __restrict__ We,    // [8][512] original layout
    const float* __restrict__ be,    // [512]
    float*       __restrict__ msg_buf) // [NE][32] edge order
{
    __shared__ float sWe2[4 * 1032];  // [l][(i*8+cc)*8 + d]
    __shared__ float sbe2[4 * 132];   // [l][i*8+cc]
    int t = threadIdx.x;
    for (int w = t; w < 4096; w += 256) {
        int d = w >> 9;            // 0..7
        int ih = w & 511;          // 0..511
        int i = ih >> 5;
        int l = (ih >> 3) & 3;
        int cc = ih & 7;
        sWe2[l * 1032 + (i * 8 + cc) * 8 + d] = We[d * 512 + ih];
    }
    for (int w = t; w < 512; w += 256) {
        int i = w >> 5, l = (w >> 3) & 3, cc = w & 7;
        sbe2[l * 132 + i * 8 + cc] = be[w];
    }
    __syncthreads();

    int gid = blockIdx.x * 256 + t;      // grid is exactly NE*4 = 800000
    int e = gid >> 2;
    int l = gid & 3;
    int src = esrc[e];

    const float4* ea4 = reinterpret_cast<const float4*>(ea) + (size_t)e * 2;
    float4 ev0 = ea4[0], ev1 = ea4[1];
    float ea8[8] = {ev0.x, ev0.y, ev0.z, ev0.w, ev1.x, ev1.y, ev1.z, ev1.w};

    float msg8[8];
    #pragma unroll
    for (int c = 0; c < 8; ++c) msg8[c] = 0.f;

    const float4* x4 = reinterpret_cast<const float4*>(x) + (size_t)src * 4;
    const float* wl = sWe2 + l * 1032;
    const float* bl = sbe2 + l * 132;

    #pragma unroll
    for (int i4 = 0; i4 < 4; ++i4) {
        float4 xv = x4[i4];
        float xs[4] = {xv.x, xv.y, xv.z, xv.w};
        #pragma unroll
        for (int ii = 0; ii < 4; ++ii) {
            int i = i4 * 4 + ii;
            const float* wbase = wl + i * 64;
            const float* bbase = bl + i * 8;
            float xi = xs[ii];
            #pragma unroll
            for (int cc = 0; cc < 8; ++cc) {
                const float* wr = wbase + cc * 8;
                float w = bbase[cc];
                #pragma unroll
                for (int d = 0; d < 8; ++d)
                    w = fmaf(ea8[d], wr[d], w);
                w = fmaxf(w, 0.f);
                msg8[cc] = fmaf(xi, w, msg8[cc]);
            }
        }
    }

    float4* mrow = reinterpret_cast<float4*>(msg_buf + (size_t)e * 32 + l * 8);
    mrow[0] = make_float4(msg8[0], msg8[1], msg8[2], msg8[3]);
    mrow[1] = make_float4(msg8[4], msg8[5], msg8[6], msg8[7]);
}

// ---- feat kernel: 4 lanes/node (R5-proven structure), eperm gather ----
__global__ __launch_bounds__(256, 4) void feat_kernel(
    const float* __restrict__ x,
    const float* __restrict__ msg_buf,
    const int*   __restrict__ eperm,
    const int*   __restrict__ row_off,
    const float* __restrict__ Wroot,   // [16][32]
    const float* __restrict__ bconv,
    const float* __restrict__ gamma,
    const float* __restrict__ beta,
    const float* __restrict__ Wlin,    // [32][32]
    const float* __restrict__ blin,
    float* __restrict__ feat)          // [NN][32]
{
    int tid = blockIdx.x * 256 + threadIdx.x;
    int n = tid >> 2;
    int l = tid & 3;
    if (n >= NN) return;
    int c0 = l * 8;

    float h8[8];
    {
        const float4* b4 = reinterpret_cast<const float4*>(bconv + c0);
        float4 a = b4[0], b = b4[1];
        h8[0]=a.x; h8[1]=a.y; h8[2]=a.z; h8[3]=a.w;
        h8[4]=b.x; h8[5]=b.y; h8[6]=b.z; h8[7]=b.w;
    }

    int start = row_off[n], end = row_off[n + 1];
    for (int k = start; k < end; ++k) {
        int e = eperm[k];
        const float4* m4 = reinterpret_cast<const float4*>(
            msg_buf + (size_t)e * HIDC + c0);
        float4 a = m4[0], b = m4[1];
        h8[0]+=a.x; h8[1]+=a.y; h8[2]+=a.z; h8[3]+=a.w;
        h8[4]+=b.x; h8[5]+=b.y; h8[6]+=b.z; h8[7]+=b.w;
    }

    const float4* x4 = reinterpret_cast<const float4*>(x) + (size_t)n * 4;
    #pragma unroll
    for (int i4 = 0; i4 < 4; ++i4) {
        float4 xv = x4[i4];
        float xsub[4] = {xv.x, xv.y, xv.z, xv.w};
        #pragma unroll
        for (int ii = 0; ii < 4; ++ii) {
            const float4* w4 = reinterpret_cast<const float4*>(
                Wroot + (i4 * 4 + ii) * HIDC + c0);
            float4 a = w4[0], b = w4[1];
            float xi = xsub[ii];
            h8[0]=fmaf(xi,a.x,h8[0]); h8[1]=fmaf(xi,a.y,h8[1]);
            h8[2]=fmaf(xi,a.z,h8[2]); h8[3]=fmaf(xi,a.w,h8[3]);
            h8[4]=fmaf(xi,b.x,h8[4]); h8[5]=fmaf(xi,b.y,h8[5]);
            h8[6]=fmaf(xi,b.z,h8[6]); h8[7]=fmaf(xi,b.w,h8[7]);
        }
    }

    // LayerNorm (quad butterfly on scalars) + ReLU
    float s = ((h8[0]+h8[1])+(h8[2]+h8[3])) + ((h8[4]+h8[5])+(h8[6]+h8[7]));
    s += __shfl_xor(s, 1);
    s += __shfl_xor(s, 2);
    float mu = s * (1.f / HIDC);
    float v = 0.f;
    #pragma unroll
    for (int c = 0; c < 8; ++c) { float d = h8[c] - mu; v = fmaf(d, d, v); }
    v += __shfl_xor(v, 1);
    v += __shfl_xor(v, 2);
    float rstd = rsqrtf(v * (1.f / HIDC) + 1e-5f);
    {
        const float4* g4 = reinterpret_cast<const float4*>(gamma + c0);
        const float4* t4 = reinterpret_cast<const float4*>(beta + c0);
        float4 g0 = g4[0], g1 = g4[1], b0 = t4[0], b1 = t4[1];
        float gs[8] = {g0.x,g0.y,g0.z,g0.w,g1.x,g1.y,g1.z,g1.w};
        float bs[8] = {b0.x,b0.y,b0.z,b0.w,b1.x,b1.y,b1.z,b1.w};
        #pragma unroll
        for (int c = 0; c < 8; ++c)
            h8[c] = fmaxf(fmaf((h8[c] - mu) * rstd, gs[c], bs[c]), 0.f);
    }

    // feat cols [c0,c0+8): broadcast h via width-4 shuffles (compile-time regs)
    float f8[8];
    {
        const float4* bl4 = reinterpret_cast<const float4*>(blin + c0);
        float4 a = bl4[0], b = bl4[1];
        f8[0]=a.x; f8[1]=a.y; f8[2]=a.z; f8[3]=a.w;
        f8[4]=b.x; f8[5]=b.y; f8[6]=b.z; f8[7]=b.w;
    }
    #pragma unroll
    for (int srcl = 0; srcl < 4; ++srcl) {
        #pragma unroll
        for (int c = 0; c < 8; ++c) {
            float hv = __shfl(h8[c], srcl, 4);   // h[srcl*8 + c]
            const float4* w4 = reinterpret_cast<const float4*>(
                Wlin + (srcl * 8 + c) * OUTC + c0);
            float4 a = w4[0], b = w4[1];
            f8[0]=fmaf(hv,a.x,f8[0]); f8[1]=fmaf(hv,a.y,f8[1]);
            f8[2]=fmaf(hv,a.z,f8[2]); f8[3]=fmaf(hv,a.w,f8[3]);
            f8[4]=fmaf(hv,b.x,f8[4]); f8[5]=fmaf(hv,b.y,f8[5]);
            f8[6]=fmaf(hv,b.z,f8[6]); f8[7]=fmaf(hv,b.w,f8[7]);
        }
    }

    float4* o4 = reinterpret_cast<float4*>(feat + (size_t)n * OUTC + c0);
    o4[0] = make_float4(f8[0], f8[1], f8[2], f8[3]);
    o4[1] = make_float4(f8[4], f8[5], f8[6], f8[7]);
}

// ---- q_head: 4 lanes/node, NO act replication.
//      phase1: lane computes acts m in [32l,32l+32) (Wq1 l-blocked in LDS)
//      phase2: lane computes q slice [8l,8l+8) from LDS acts + L1-hot Wq2. ----
#define QH_W1  0                 // 4*1032 = 4128 words
#define QH_ACT 4128              // 64*136 = 8704 words
#define QH_TOT (4128 + 8704)     // 12832 words = 51328 B

__global__ __launch_bounds__(256, 3) void qhead_kernel(
    const float* __restrict__ feat,    // [NN][32]
    const float* __restrict__ Wq1,     // [32][128] original layout
    const float* __restrict__ bq1,
    const float* __restrict__ Wq2,     // [128][32]
    const float* __restrict__ bq2,
    float* __restrict__ out)
{
    __shared__ float sm[QH_TOT];
    int t = threadIdx.x;
    for (int w = t; w < 4096; w += 256) {
        int k = w >> 7, m = w & 127, l = m >> 5, j = m & 31;
        sm[QH_W1 + l * 1032 + k * 32 + j] = Wq1[w];
    }
    __syncthreads();

    int gid = blockIdx.x * 256 + t;
    int n = gid >> 2;
    int l = gid & 3;
    int nl = t >> 2;                       // node-local 0..63
    int nc = (n < NN) ? n : (NN - 1);      // clamp for loads (no early return: barriers)

    float f[OUTC];
    const float4* f4 = reinterpret_cast<const float4*>(feat + (size_t)nc * 32);
    #pragma unroll
    for (int i = 0; i < 8; ++i) {
        float4 v = f4[i];
        f[i*4+0]=v.x; f[i*4+1]=v.y; f[i*4+2]=v.z; f[i*4+3]=v.w;
    }

    // phase 1: acts for m in [32l, 32l+32)
    float acc[32];
    {
        const float4* b4 = reinterpret_cast<const float4*>(bq1 + l * 32);
        #pragma unroll
        for (int j4 = 0; j4 < 8; ++j4) {
            float4 b = b4[j4];
            acc[j4*4+0]=b.x; acc[j4*4+1]=b.y; acc[j4*4+2]=b.z; acc[j4*4+3]=b.w;
        }
    }
    const float* w1 = sm + QH_W1 + l * 1032;
    #pragma unroll 4
    for (int k = 0; k < 32; ++k) {
        float fk = f[k];
        const float* wr = w1 + k * 32;
        #pragma unroll
        for (int j = 0; j < 32; ++j)
            acc[j] = fmaf(fk, wr[j], acc[j]);
    }
    float* act = sm + QH_ACT + nl * 136 + l * 32;
    #pragma unroll
    for (int j = 0; j < 32; ++j) act[j] = fmaxf(acc[j], 0.f);
    __syncthreads();

    // phase 2: q slice [8l, 8l+8)
    float q8[8];
    {
        const float4* b4 = reinterpret_cast<const float4*>(bq2 + l * 8);
        float4 a = b4[0], b = b4[1];
        q8[0]=a.x; q8[1]=a.y; q8[2]=a.z; q8[3]=a.w;
        q8[4]=b.x; q8[5]=b.y; q8[6]=b.z; q8[7]=b.w;
    }
    const float* actn = sm + QH_ACT + nl * 136;
    #pragma unroll 4
    for (int m4 = 0; m4 < 32; ++m4) {
        const float4* a4 = reinterpret_cast<const float4*>(actn + m4 * 4);
        float4 av = a4[0];
        float am[4] = {av.x, av.y, av.z, av.w};
        #pragma unroll
        for (int mm = 0; mm < 4; ++mm) {
            int m = m4 * 4 + mm;
            const float4* w2 = reinterpret_cast<const float4*>(Wq2 + m * NACT + l * 8);
            float4 wa = w2[0], wb = w2[1];
            float a = am[mm];
            q8[0]=fmaf(a,wa.x,q8[0]); q8[1]=fmaf(a,wa.y,q8[1]);
            q8[2]=fmaf(a,wa.z,q8[2]); q8[3]=fmaf(a,wa.w,q8[3]);
            q8[4]=fmaf(a,wb.x,q8[4]); q8[5]=fmaf(a,wb.y,q8[5]);
            q8[6]=fmaf(a,wb.z,q8[6]); q8[7]=fmaf(a,wb.w,q8[7]);
        }
    }

    if (n < NN) {
        float4* o4 = reinterpret_cast<float4*>(out + (size_t)n * NACT + l * 8);
        o4[0] = make_float4(q8[0], q8[1], q8[2], q8[3]);
        o4[1] = make_float4(q8[4], q8[5], q8[6], q8[7]);
    }
}

extern "C" void kernel_launch(void* const* d_in, const int* in_sizes, int n_in,
                              void* d_out, int out_size, void* d_ws, size_t ws_size,
                              hipStream_t stream) {
    const float* x     = (const float*)d_in[0];
    const int*   esrc  = (const int*)d_in[1];
    const int*   edst  = (const int*)d_in[2];
    const float* ea    = (const float*)d_in[3];
    const float* We    = (const float*)d_in[4];
    const float* be    = (const float*)d_in[5];
    const float* Wroot = (const float*)d_in[6];
    const float* bconv = (const float*)d_in[7];
    const float* gamma = (const float*)d_in[8];
    const float* beta  = (const float*)d_in[9];
    const float* Wlin  = (const float*)d_in[10];
    const float* blin  = (const float*)d_in[11];
    const float* Wq1   = (const float*)d_in[12];
    const float* bq1   = (const float*)d_in[13];
    const float* Wq2   = (const float*)d_in[14];
    const float* bq2   = (const float*)d_in[15];
    float* out = (float*)d_out;

    // workspace layout (bytes)
    char* ws = (char*)d_ws;
    int*   deg     = (int*)(ws + 0);          // 200704
    int*   cursor  = (int*)(ws + 200704);     // 200704
    int*   row_off = (int*)(ws + 401408);     // 201728
    int*   partials= (int*)(ws + 603136);     // 1024
    int*   poff    = (int*)(ws + 604160);     // 1024
    int*   eperm   = (int*)(ws + 605184);     // 800768
    float* msg_buf = (float*)(ws + 1405952);  // 25.6 MB
    float* featb   = (float*)(ws + 27005952); // 6.4 MB

    hipMemsetAsync(deg, 0, 2 * 200704, stream);   // deg + cursor (adjacent)

    edge_q_kernel<<<NE * 4 / 256, 256, 0, stream>>>(x, esrc, ea, We, be, msg_buf);
    hist_kernel<<<(NE + 255) / 256, 256, 0, stream>>>(edst, deg);
    partial_kernel<<<NPART, 256, 0, stream>>>(deg, partials);
    scan_partials_kernel<<<1, 256, 0, stream>>>(partials, poff);
    rowoff_kernel<<<NPART, 256, 0, stream>>>(deg, poff, row_off);
    build_perm_kernel<<<(NE + 255) / 256, 256, 0, stream>>>(edst, row_off, cursor, eperm);
    feat_kernel<<<(NN * 4 + 255) / 256, 256, 0, stream>>>(x, msg_buf, eperm, row_off,
                                                          Wroot, bconv, gamma, beta,
                                                          Wlin, blin, featb);
    qhead_kernel<<<(NN * 4 + 255) / 256, 256, 0, stream>>>(featb, Wq1, bq1,
                                                           Wq2, bq2, out);
}

// Round 10
// 160.370 us; speedup vs baseline: 1.1480x; 1.1106x over previous
//
#include <hip/hip_runtime.h>

#define NN   50000
#define NE   200000
#define INC  16
#define HIDC 32
#define EDGED 8
#define OUTC 32
#define MLPH 128
#define NACT 32

#define NPART 196   // ceil(NN / 256)

// ---- degree histogram ----
__global__ __launch_bounds__(256) void hist_kernel(const int* __restrict__ edst,
                                                   int* __restrict__ deg) {
    int e = blockIdx.x * blockDim.x + threadIdx.x;
    if (e < NE) atomicAdd(&deg[edst[e]], 1);
}

// ---- scan pass 1: per-block sums ----
__global__ __launch_bounds__(256) void partial_kernel(const int* __restrict__ deg,
                                                      int* __restrict__ partials) {
    __shared__ int sm[256];
    int t = threadIdx.x, i = blockIdx.x * 256 + t;
    sm[t] = (i < NN) ? deg[i] : 0;
    __syncthreads();
    #pragma unroll
    for (int off = 128; off > 0; off >>= 1) {
        if (t < off) sm[t] += sm[t + off];
        __syncthreads();
    }
    if (t == 0) partials[blockIdx.x] = sm[0];
}

// ---- scan pass 2: exclusive scan of 196 partials ----
__global__ __launch_bounds__(256) void scan_partials_kernel(const int* __restrict__ partials,
                                                            int* __restrict__ poff) {
    __shared__ int sm[256];
    int t = threadIdx.x;
    sm[t] = (t < NPART) ? partials[t] : 0;
    __syncthreads();
    for (int off = 1; off < 256; off <<= 1) {
        int v = (t >= off) ? sm[t - off] : 0;
        __syncthreads();
        sm[t] += v;
        __syncthreads();
    }
    poff[t] = (t == 0) ? 0 : sm[t - 1];
}

// ---- scan pass 3: block-local scan + base -> row_off ----
__global__ __launch_bounds__(256) void rowoff_kernel(const int* __restrict__ deg,
                                                     const int* __restrict__ poff,
                                                     int* __restrict__ row_off) {
    __shared__ int sm[256];
    int t = threadIdx.x, i = blockIdx.x * 256 + t;
    int d = (i < NN) ? deg[i] : 0;
    sm[t] = d;
    __syncthreads();
    for (int off = 1; off < 256; off <<= 1) {
        int v = (t >= off) ? sm[t - off] : 0;
        __syncthreads();
        sm[t] += v;
        __syncthreads();
    }
    int excl = sm[t] - d + poff[blockIdx.x];
    if (i < NN) {
        row_off[i] = excl;
        if (i == NN - 1) row_off[NN] = excl + d;   // == NE
    }
}

// ---- build permutation: eperm[pos] = e ----
__global__ __launch_bounds__(256) void build_perm_kernel(const int* __restrict__ edst,
                                                         const int* __restrict__ row_off,
                                                         int* __restrict__ cursor,
                                                         int* __restrict__ eperm) {
    int e = blockIdx.x * blockDim.x + threadIdx.x;
    if (e < NE) {
        int dst = edst[e];
        int pos = row_off[dst] + atomicAdd(&cursor[dst], 1);
        eperm[pos] = e;
    }
}

// ---- edge kernel: quad (4 lanes) per edge-group, 4 EDGES per thread.
//      Each LDS weight read feeds 4 edges x 8 FMA (register reuse).
//      l-staggered LDS layout: stride 1032 words -> banks {0,8,16,24}. ----
__global__ __launch_bounds__(256, 3) void edge_q4_kernel(
    const float* __restrict__ x,
    const int*   __restrict__ esrc,
    const float* __restrict__ ea,
    const float* __restrict__ We,      // [8][512] original layout
    const float* __restrict__ be,      // [512]
    float*       __restrict__ msg_buf) // [NE][32] edge order
{
    __shared__ float sWe2[4 * 1032];  // [l][(i*8+cc)*8 + d]
    __shared__ float sbe2[4 * 132];   // [l][i*8+cc]
    int t = threadIdx.x;
    for (int w = t; w < 4096; w += 256) {
        int d = w >> 9, ih = w & 511;
        int i = ih >> 5, l = (ih >> 3) & 3, cc = ih & 7;
        sWe2[l * 1032 + (i * 8 + cc) * 8 + d] = We[d * 512 + ih];
    }
    for (int w = t; w < 512; w += 256) {
        int i = w >> 5, l = (w >> 3) & 3, cc = w & 7;
        sbe2[l * 132 + i * 8 + cc] = be[w];
    }
    __syncthreads();

    int Q = blockIdx.x * 64 + (t >> 2);
    int l = t & 3;
    if (Q >= NE / 4) return;

    int e0 = Q, e1 = Q + 50000, e2 = Q + 100000, e3 = Q + 150000;
    int s0 = esrc[e0], s1 = esrc[e1], s2 = esrc[e2], s3 = esrc[e3];

    float ea0[8], ea1[8], ea2[8], ea3[8];
    {
        const float4* p;
        float4 a, b;
        p = reinterpret_cast<const float4*>(ea) + (size_t)e0 * 2; a = p[0]; b = p[1];
        ea0[0]=a.x; ea0[1]=a.y; ea0[2]=a.z; ea0[3]=a.w; ea0[4]=b.x; ea0[5]=b.y; ea0[6]=b.z; ea0[7]=b.w;
        p = reinterpret_cast<const float4*>(ea) + (size_t)e1 * 2; a = p[0]; b = p[1];
        ea1[0]=a.x; ea1[1]=a.y; ea1[2]=a.z; ea1[3]=a.w; ea1[4]=b.x; ea1[5]=b.y; ea1[6]=b.z; ea1[7]=b.w;
        p = reinterpret_cast<const float4*>(ea) + (size_t)e2 * 2; a = p[0]; b = p[1];
        ea2[0]=a.x; ea2[1]=a.y; ea2[2]=a.z; ea2[3]=a.w; ea2[4]=b.x; ea2[5]=b.y; ea2[6]=b.z; ea2[7]=b.w;
        p = reinterpret_cast<const float4*>(ea) + (size_t)e3 * 2; a = p[0]; b = p[1];
        ea3[0]=a.x; ea3[1]=a.y; ea3[2]=a.z; ea3[3]=a.w; ea3[4]=b.x; ea3[5]=b.y; ea3[6]=b.z; ea3[7]=b.w;
    }

    float m0[8], m1[8], m2[8], m3[8];
    #pragma unroll
    for (int c = 0; c < 8; ++c) { m0[c]=0.f; m1[c]=0.f; m2[c]=0.f; m3[c]=0.f; }

    const float* wl = sWe2 + l * 1032;
    const float* bl = sbe2 + l * 132;
    const float4* xp0 = reinterpret_cast<const float4*>(x) + (size_t)s0 * 4;
    const float4* xp1 = reinterpret_cast<const float4*>(x) + (size_t)s1 * 4;
    const float4* xp2 = reinterpret_cast<const float4*>(x) + (size_t)s2 * 4;
    const float4* xp3 = reinterpret_cast<const float4*>(x) + (size_t)s3 * 4;

    for (int i4 = 0; i4 < 4; ++i4) {        // rolled: keeps code I$-sized
        float4 xv0 = xp0[i4], xv1 = xp1[i4], xv2 = xp2[i4], xv3 = xp3[i4];
        float xs0[4] = {xv0.x, xv0.y, xv0.z, xv0.w};
        float xs1[4] = {xv1.x, xv1.y, xv1.z, xv1.w};
        float xs2[4] = {xv2.x, xv2.y, xv2.z, xv2.w};
        float xs3[4] = {xv3.x, xv3.y, xv3.z, xv3.w};
        const float* wb4 = wl + i4 * 256;   // 4 i's x 64
        const float* bb4 = bl + i4 * 32;
        #pragma unroll
        for (int ii = 0; ii < 4; ++ii) {
            const float* wbase = wb4 + ii * 64;
            const float* bbase = bb4 + ii * 8;
            float xi0 = xs0[ii], xi1 = xs1[ii], xi2 = xs2[ii], xi3 = xs3[ii];
            #pragma unroll
            for (int cc = 0; cc < 8; ++cc) {
                const float* wr = wbase + cc * 8;
                float bv = bbase[cc];
                float w0 = bv, w1 = bv, w2 = bv, w3 = bv;
                #pragma unroll
                for (int d = 0; d < 8; ++d) {
                    float wd = wr[d];
                    w0 = fmaf(ea0[d], wd, w0);
                    w1 = fmaf(ea1[d], wd, w1);
                    w2 = fmaf(ea2[d], wd, w2);
                    w3 = fmaf(ea3[d], wd, w3);
                }
                w0 = fmaxf(w0, 0.f); w1 = fmaxf(w1, 0.f);
                w2 = fmaxf(w2, 0.f); w3 = fmaxf(w3, 0.f);
                m0[cc] = fmaf(xi0, w0, m0[cc]);
                m1[cc] = fmaf(xi1, w1, m1[cc]);
                m2[cc] = fmaf(xi2, w2, m2[cc]);
                m3[cc] = fmaf(xi3, w3, m3[cc]);
            }
        }
    }

    float4* o;
    o = reinterpret_cast<float4*>(msg_buf + (size_t)e0 * 32 + l * 8);
    o[0] = make_float4(m0[0], m0[1], m0[2], m0[3]);
    o[1] = make_float4(m0[4], m0[5], m0[6], m0[7]);
    o = reinterpret_cast<float4*>(msg_buf + (size_t)e1 * 32 + l * 8);
    o[0] = make_float4(m1[0], m1[1], m1[2], m1[3]);
    o[1] = make_float4(m1[4], m1[5], m1[6], m1[7]);
    o = reinterpret_cast<float4*>(msg_buf + (size_t)e2 * 32 + l * 8);
    o[0] = make_float4(m2[0], m2[1], m2[2], m2[3]);
    o[1] = make_float4(m2[4], m2[5], m2[6], m2[7]);
    o = reinterpret_cast<float4*>(msg_buf + (size_t)e3 * 32 + l * 8);
    o[0] = make_float4(m3[0], m3[1], m3[2], m3[3]);
    o[1] = make_float4(m3[4], m3[5], m3[6], m3[7]);
}

// ---- feat kernel: 4 lanes/node, eperm gather (unchanged, proven) ----
__global__ __launch_bounds__(256, 4) void feat_kernel(
    const float* __restrict__ x,
    const float* __restrict__ msg_buf,
    const int*   __restrict__ eperm,
    const int*   __restrict__ row_off,
    const float* __restrict__ Wroot,   // [16][32]
    const float* __restrict__ bconv,
    const float* __restrict__ gamma,
    const float* __restrict__ beta,
    const float* __restrict__ Wlin,    // [32][32]
    const float* __restrict__ blin,
    float* __restrict__ feat)          // [NN][32]
{
    int tid = blockIdx.x * 256 + threadIdx.x;
    int n = tid >> 2;
    int l = tid & 3;
    if (n >= NN) return;
    int c0 = l * 8;

    float h8[8];
    {
        const float4* b4 = reinterpret_cast<const float4*>(bconv + c0);
        float4 a = b4[0], b = b4[1];
        h8[0]=a.x; h8[1]=a.y; h8[2]=a.z; h8[3]=a.w;
        h8[4]=b.x; h8[5]=b.y; h8[6]=b.z; h8[7]=b.w;
    }

    int start = row_off[n], end = row_off[n + 1];
    for (int k = start; k < end; ++k) {
        int e = eperm[k];
        const float4* m4 = reinterpret_cast<const float4*>(
            msg_buf + (size_t)e * HIDC + c0);
        float4 a = m4[0], b = m4[1];
        h8[0]+=a.x; h8[1]+=a.y; h8[2]+=a.z; h8[3]+=a.w;
        h8[4]+=b.x; h8[5]+=b.y; h8[6]+=b.z; h8[7]+=b.w;
    }

    const float4* x4 = reinterpret_cast<const float4*>(x) + (size_t)n * 4;
    #pragma unroll
    for (int i4 = 0; i4 < 4; ++i4) {
        float4 xv = x4[i4];
        float xsub[4] = {xv.x, xv.y, xv.z, xv.w};
        #pragma unroll
        for (int ii = 0; ii < 4; ++ii) {
            const float4* w4 = reinterpret_cast<const float4*>(
                Wroot + (i4 * 4 + ii) * HIDC + c0);
            float4 a = w4[0], b = w4[1];
            float xi = xsub[ii];
            h8[0]=fmaf(xi,a.x,h8[0]); h8[1]=fmaf(xi,a.y,h8[1]);
            h8[2]=fmaf(xi,a.z,h8[2]); h8[3]=fmaf(xi,a.w,h8[3]);
            h8[4]=fmaf(xi,b.x,h8[4]); h8[5]=fmaf(xi,b.y,h8[5]);
            h8[6]=fmaf(xi,b.z,h8[6]); h8[7]=fmaf(xi,b.w,h8[7]);
        }
    }

    float s = ((h8[0]+h8[1])+(h8[2]+h8[3])) + ((h8[4]+h8[5])+(h8[6]+h8[7]));
    s += __shfl_xor(s, 1);
    s += __shfl_xor(s, 2);
    float mu = s * (1.f / HIDC);
    float v = 0.f;
    #pragma unroll
    for (int c = 0; c < 8; ++c) { float d = h8[c] - mu; v = fmaf(d, d, v); }
    v += __shfl_xor(v, 1);
    v += __shfl_xor(v, 2);
    float rstd = rsqrtf(v * (1.f / HIDC) + 1e-5f);
    {
        const float4* g4 = reinterpret_cast<const float4*>(gamma + c0);
        const float4* t4 = reinterpret_cast<const float4*>(beta + c0);
        float4 g0 = g4[0], g1 = g4[1], b0 = t4[0], b1 = t4[1];
        float gs[8] = {g0.x,g0.y,g0.z,g0.w,g1.x,g1.y,g1.z,g1.w};
        float bs[8] = {b0.x,b0.y,b0.z,b0.w,b1.x,b1.y,b1.z,b1.w};
        #pragma unroll
        for (int c = 0; c < 8; ++c)
            h8[c] = fmaxf(fmaf((h8[c] - mu) * rstd, gs[c], bs[c]), 0.f);
    }

    float f8[8];
    {
        const float4* bl4 = reinterpret_cast<const float4*>(blin + c0);
        float4 a = bl4[0], b = bl4[1];
        f8[0]=a.x; f8[1]=a.y; f8[2]=a.z; f8[3]=a.w;
        f8[4]=b.x; f8[5]=b.y; f8[6]=b.z; f8[7]=b.w;
    }
    #pragma unroll
    for (int srcl = 0; srcl < 4; ++srcl) {
        #pragma unroll
        for (int c = 0; c < 8; ++c) {
            float hv = __shfl(h8[c], srcl, 4);   // h[srcl*8 + c]
            const float4* w4 = reinterpret_cast<const float4*>(
                Wlin + (srcl * 8 + c) * OUTC + c0);
            float4 a = w4[0], b = w4[1];
            f8[0]=fmaf(hv,a.x,f8[0]); f8[1]=fmaf(hv,a.y,f8[1]);
            f8[2]=fmaf(hv,a.z,f8[2]); f8[3]=fmaf(hv,a.w,f8[3]);
            f8[4]=fmaf(hv,b.x,f8[4]); f8[5]=fmaf(hv,b.y,f8[5]);
            f8[6]=fmaf(hv,b.z,f8[6]); f8[7]=fmaf(hv,b.w,f8[7]);
        }
    }

    float4* o4 = reinterpret_cast<float4*>(feat + (size_t)n * OUTC + c0);
    o4[0] = make_float4(f8[0], f8[1], f8[2], f8[3]);
    o4[1] = make_float4(f8[4], f8[5], f8[6], f8[7]);
}

// ---- q_head v2: quad per NODE-PAIR (2 nodes/thread), lane l computes
//      acts m in [32l,32l+32) for both nodes (Wq1 from LDS, reuse x2),
//      act exchange via quad __shfl (no LDS act buffer, no barrier),
//      Wq2 from global/L1 (separate vmem pipe balances LDS pipe). ----
__global__ __launch_bounds__(256, 3) void qhead_kernel(
    const float* __restrict__ feat,    // [NN][32]
    const float* __restrict__ Wq1,     // [32][128] original layout
    const float* __restrict__ bq1,
    const float* __restrict__ Wq2,     // [128][32]
    const float* __restrict__ bq2,
    float* __restrict__ out)
{
    __shared__ float sw1[4 * 1032];    // [l][k*32+j], stagger 1032
    int t = threadIdx.x;
    for (int w = t; w < 4096; w += 256) {
        int k = w >> 7, m = w & 127, l = m >> 5, j = m & 31;
        sw1[l * 1032 + k * 32 + j] = Wq1[w];
    }
    __syncthreads();

    int gid = blockIdx.x * 256 + t;
    int p = gid >> 2;                  // node pair
    int l = gid & 3;
    if (p >= NN / 2) return;
    int n0 = p * 2, n1 = p * 2 + 1;

    float f0[OUTC], f1[OUTC];
    {
        const float4* a4 = reinterpret_cast<const float4*>(feat + (size_t)n0 * 32);
        const float4* b4 = reinterpret_cast<const float4*>(feat + (size_t)n1 * 32);
        #pragma unroll
        for (int i = 0; i < 8; ++i) {
            float4 a = a4[i], b = b4[i];
            f0[i*4+0]=a.x; f0[i*4+1]=a.y; f0[i*4+2]=a.z; f0[i*4+3]=a.w;
            f1[i*4+0]=b.x; f1[i*4+1]=b.y; f1[i*4+2]=b.z; f1[i*4+3]=b.w;
        }
    }

    // phase 1: acts m in [32l, 32l+32) for both nodes
    float acc0[32], acc1[32];
    {
        const float4* b4 = reinterpret_cast<const float4*>(bq1 + l * 32);
        #pragma unroll
        for (int j4 = 0; j4 < 8; ++j4) {
            float4 b = b4[j4];
            acc0[j4*4+0]=b.x; acc0[j4*4+1]=b.y; acc0[j4*4+2]=b.z; acc0[j4*4+3]=b.w;
            acc1[j4*4+0]=b.x; acc1[j4*4+1]=b.y; acc1[j4*4+2]=b.z; acc1[j4*4+3]=b.w;
        }
    }
    const float* w1 = sw1 + l * 1032;
    #pragma unroll
    for (int k = 0; k < 32; ++k) {
        float fk0 = f0[k], fk1 = f1[k];
        const float* wr = w1 + k * 32;
        #pragma unroll
        for (int j = 0; j < 32; ++j) {
            float wj = wr[j];
            acc0[j] = fmaf(fk0, wj, acc0[j]);
            acc1[j] = fmaf(fk1, wj, acc1[j]);
        }
    }
    #pragma unroll
    for (int j = 0; j < 32; ++j) {
        acc0[j] = fmaxf(acc0[j], 0.f);
        acc1[j] = fmaxf(acc1[j], 0.f);
    }

    // phase 2: q slice [8l,8l+8) for both nodes; acts via quad shfl
    float q0[8], q1[8];
    {
        const float4* b4 = reinterpret_cast<const float4*>(bq2 + l * 8);
        float4 a = b4[0], b = b4[1];
        q0[0]=a.x; q0[1]=a.y; q0[2]=a.z; q0[3]=a.w;
        q0[4]=b.x; q0[5]=b.y; q0[6]=b.z; q0[7]=b.w;
        #pragma unroll
        for (int c = 0; c < 8; ++c) q1[c] = q0[c];
    }
    #pragma unroll
    for (int srcl = 0; srcl < 4; ++srcl) {
        #pragma unroll
        for (int j = 0; j < 32; ++j) {
            float a0 = __shfl(acc0[j], srcl, 4);
            float a1 = __shfl(acc1[j], srcl, 4);
            int m = srcl * 32 + j;
            const float4* w2 = reinterpret_cast<const float4*>(Wq2 + m * NACT + l * 8);
            float4 wa = w2[0], wb = w2[1];
            q0[0]=fmaf(a0,wa.x,q0[0]); q0[1]=fmaf(a0,wa.y,q0[1]);
            q0[2]=fmaf(a0,wa.z,q0[2]); q0[3]=fmaf(a0,wa.w,q0[3]);
            q0[4]=fmaf(a0,wb.x,q0[4]); q0[5]=fmaf(a0,wb.y,q0[5]);
            q0[6]=fmaf(a0,wb.z,q0[6]); q0[7]=fmaf(a0,wb.w,q0[7]);
            q1[0]=fmaf(a1,wa.x,q1[0]); q1[1]=fmaf(a1,wa.y,q1[1]);
            q1[2]=fmaf(a1,wa.z,q1[2]); q1[3]=fmaf(a1,wa.w,q1[3]);
            q1[4]=fmaf(a1,wb.x,q1[4]); q1[5]=fmaf(a1,wb.y,q1[5]);
            q1[6]=fmaf(a1,wb.z,q1[6]); q1[7]=fmaf(a1,wb.w,q1[7]);
        }
    }

    float4* o;
    o = reinterpret_cast<float4*>(out + (size_t)n0 * NACT + l * 8);
    o[0] = make_float4(q0[0], q0[1], q0[2], q0[3]);
    o[1] = make_float4(q0[4], q0[5], q0[6], q0[7]);
    o = reinterpret_cast<float4*>(out + (size_t)n1 * NACT + l * 8);
    o[0] = make_float4(q1[0], q1[1], q1[2], q1[3]);
    o[1] = make_float4(q1[4], q1[5], q1[6], q1[7]);
}

extern "C" void kernel_launch(void* const* d_in, const int* in_sizes, int n_in,
                              void* d_out, int out_size, void* d_ws, size_t ws_size,
                              hipStream_t stream) {
    const float* x     = (const float*)d_in[0];
    const int*   esrc  = (const int*)d_in[1];
    const int*   edst  = (const int*)d_in[2];
    const float* ea    = (const float*)d_in[3];
    const float* We    = (const float*)d_in[4];
    const float* be    = (const float*)d_in[5];
    const float* Wroot = (const float*)d_in[6];
    const float* bconv = (const float*)d_in[7];
    const float* gamma = (const float*)d_in[8];
    const float* beta  = (const float*)d_in[9];
    const float* Wlin  = (const float*)d_in[10];
    const float* blin  = (const float*)d_in[11];
    const float* Wq1   = (const float*)d_in[12];
    const float* bq1   = (const float*)d_in[13];
    const float* Wq2   = (const float*)d_in[14];
    const float* bq2   = (const float*)d_in[15];
    float* out = (float*)d_out;

    // workspace layout (bytes)
    char* ws = (char*)d_ws;
    int*   deg     = (int*)(ws + 0);          // 200704
    int*   cursor  = (int*)(ws + 200704);     // 200704
    int*   row_off = (int*)(ws + 401408);     // 201728
    int*   partials= (int*)(ws + 603136);     // 1024
    int*   poff    = (int*)(ws + 604160);     // 1024
    int*   eperm   = (int*)(ws + 605184);     // 800768
    float* msg_buf = (float*)(ws + 1405952);  // 25.6 MB
    float* featb   = (float*)(ws + 27005952); // 6.4 MB

    hipMemsetAsync(deg, 0, 2 * 200704, stream);   // deg + cursor (adjacent)

    edge_q4_kernel<<<(NE / 4 + 63) / 64, 256, 0, stream>>>(x, esrc, ea, We, be, msg_buf);
    hist_kernel<<<(NE + 255) / 256, 256, 0, stream>>>(edst, deg);
    partial_kernel<<<NPART, 256, 0, stream>>>(deg, partials);
    scan_partials_kernel<<<1, 256, 0, stream>>>(partials, poff);
    rowoff_kernel<<<NPART, 256, 0, stream>>>(deg, poff, row_off);
    build_perm_kernel<<<(NE + 255) / 256, 256, 0, stream>>>(edst, row_off, cursor, eperm);
    feat_kernel<<<(NN * 4 + 255) / 256, 256, 0, stream>>>(x, msg_buf, eperm, row_off,
                                                          Wroot, bconv, gamma, beta,
                                                          Wlin, blin, featb);
    qhead_kernel<<<(NN / 2 * 4 + 255) / 256, 256, 0, stream>>>(featb, Wq1, bq1,
                                                               Wq2, bq2, out);
}